// Round 1
// baseline (362.740 us; speedup 1.0000x reference)
//
#include <hip/hip_runtime.h>
#include <math.h>

#define NTOK 50257
#define NHID 1024
#define NPC  225
#define NCLS 224
#define BATCH 1024

// ws layout (bytes):
//   0     : int   nitems
//   64    : int   order[1024]      (sample ids sorted by class)
//   8192  : int4  items[384]       (cls, s0, nt, 0)
//   16384 : float p_top[1024]
#define WS_ORDER_OFS 16      // in ints
#define WS_ITEMS_OFS 8192    // in bytes
#define WS_PTOP_OFS  16384   // in bytes
#define MAX_ITEMS    352

// ---------------------------------------------------------------------------
// K0: group samples by class, build work items (<=8 samples each)
// ---------------------------------------------------------------------------
__global__ __launch_bounds__(256) void k0_group(const int* __restrict__ labels,
                                                int* __restrict__ ws)
{
    __shared__ int cnt[256];
    __shared__ int scan[256];
    __shared__ int iscan[256];
    __shared__ int cur[256];
    const int tid = threadIdx.x;

    cnt[tid] = 0;
    __syncthreads();
    for (int i = tid; i < BATCH; i += 256)
        atomicAdd(&cnt[labels[i] / NPC], 1);
    __syncthreads();

    const int myc = (tid < NCLS) ? cnt[tid] : 0;
    const int myi = (myc + 7) >> 3;   // items for this class
    scan[tid]  = myc;
    iscan[tid] = myi;
    __syncthreads();
    // Hillis-Steele inclusive scans
    for (int off = 1; off < 256; off <<= 1) {
        int a = (tid >= off) ? scan[tid - off]  : 0;
        int b = (tid >= off) ? iscan[tid - off] : 0;
        __syncthreads();
        scan[tid]  += a;
        iscan[tid] += b;
        __syncthreads();
    }
    const int sbase = scan[tid]  - myc;   // exclusive prefix
    const int ibase = iscan[tid] - myi;
    if (tid == 255) ws[0] = iscan[255];
    cur[tid] = sbase;

    int4* items = (int4*)((char*)ws + WS_ITEMS_OFS);
    if (tid < NCLS) {
        for (int t = 0; t < myi; ++t)
            items[ibase + t] = make_int4(tid, sbase + 8 * t, min(8, myc - 8 * t), 0);
    }
    __syncthreads();

    int* order = ws + WS_ORDER_OFS;
    for (int i = tid; i < BATCH; i += 256) {
        int c = labels[i] / NPC;
        int p = atomicAdd(&cur[c], 1);
        order[p] = i;
    }
}

// ---------------------------------------------------------------------------
// K1: top logits + softmax -> p_top[s].  8 samples per block, 4 waves split d.
// ---------------------------------------------------------------------------
__global__ __launch_bounds__(256) void k1_top(const float* __restrict__ X,
                                              const int* __restrict__ labels,
                                              const float* __restrict__ Wt,
                                              const float* __restrict__ bt,
                                              float* __restrict__ ptop)
{
    __shared__ __align__(16) float smem[12288]; // in_t[1024][12] / red[4][8][232]
    const int tid  = threadIdx.x;
    const int wave = tid >> 6;
    const int lane = tid & 63;
    const int sbase = blockIdx.x * 8;

    // stage 8 input rows, transposed: smem[dd*12 + j] = X[sbase+j][dd]
    for (int idx = tid; idx < 8 * NHID; idx += 256) {
        int j = idx >> 10, dd = idx & 1023;
        smem[dd * 12 + j] = X[(sbase + j) * NHID + dd];
    }
    __syncthreads();

    float acc[8][4];
#pragma unroll
    for (int j = 0; j < 8; ++j)
#pragma unroll
        for (int k = 0; k < 4; ++k) acc[j][k] = 0.f;

    const int d0 = wave * 256;
#pragma unroll 4
    for (int dd = d0; dd < d0 + 256; ++dd) {
        float w[4];
        w[0] = Wt[dd * NCLS + lane];
        w[1] = Wt[dd * NCLS + lane + 64];
        w[2] = Wt[dd * NCLS + lane + 128];
        w[3] = (lane < 32) ? Wt[dd * NCLS + lane + 192] : 0.f;
        float4 a = *(const float4*)&smem[dd * 12 + 0];
        float4 b = *(const float4*)&smem[dd * 12 + 4];
        float xi[8] = {a.x, a.y, a.z, a.w, b.x, b.y, b.z, b.w};
#pragma unroll
        for (int j = 0; j < 8; ++j)
#pragma unroll
            for (int k = 0; k < 4; ++k) acc[j][k] += xi[j] * w[k];
    }
    __syncthreads();   // done with in_t

    float* red = smem; // red[w][j][232]
#pragma unroll
    for (int j = 0; j < 8; ++j)
#pragma unroll
        for (int k = 0; k < 4; ++k) {
            int c = lane + 64 * k;
            if (c < NCLS) red[(wave * 8 + j) * 232 + c] = acc[j][k];
        }
    __syncthreads();

    // softmax: wave w handles samples 2w, 2w+1
    for (int jj = 0; jj < 2; ++jj) {
        const int j = wave * 2 + jj;
        const int s = sbase + j;
        float v[4];
#pragma unroll
        for (int k = 0; k < 4; ++k) {
            int c = lane + 64 * k;
            v[k] = (c < NCLS)
                     ? (red[(0 * 8 + j) * 232 + c] + red[(1 * 8 + j) * 232 + c] +
                        red[(2 * 8 + j) * 232 + c] + red[(3 * 8 + j) * 232 + c] + bt[c])
                     : -INFINITY;
        }
        float m = fmaxf(fmaxf(v[0], v[1]), fmaxf(v[2], v[3]));
        for (int o = 32; o > 0; o >>= 1) m = fmaxf(m, __shfl_xor(m, o));
        float e = expf(v[0] - m) + expf(v[1] - m) + expf(v[2] - m) + expf(v[3] - m);
        for (int o = 32; o > 0; o >>= 1) e += __shfl_xor(e, o);
        const int pt = labels[s] / NPC;
        if (lane == (pt & 63))
            ptop[s] = expf(v[pt >> 6] - m) / e;
    }
}

// ---------------------------------------------------------------------------
// K2: bottom logits per class-item + softmax + final multiply -> out[s]
// ---------------------------------------------------------------------------
__global__ __launch_bounds__(256) void k2_bottom(const float* __restrict__ X,
                                                 const int* __restrict__ labels,
                                                 const float* __restrict__ Wb,
                                                 const float* __restrict__ bb,
                                                 const int* __restrict__ ws,
                                                 const float* __restrict__ ptop,
                                                 float* __restrict__ out)
{
    __shared__ __align__(16) float smem[12288];
    const int nitems = ws[0];
    if ((int)blockIdx.x >= nitems) return;
    const int4 item = ((const int4*)((const char*)ws + WS_ITEMS_OFS))[blockIdx.x];
    const int cls = item.x, s0 = item.y, nt = item.z;
    const int* order = ws + WS_ORDER_OFS;

    const int tid  = threadIdx.x;
    const int wave = tid >> 6;
    const int lane = tid & 63;

    // stage up to 8 gathered input rows (zero-pad unused slots)
    for (int idx = tid; idx < 8 * NHID; idx += 256) {
        int j = idx >> 10, dd = idx & 1023;
        float v = 0.f;
        if (j < nt) v = X[order[s0 + j] * NHID + dd];
        smem[dd * 12 + j] = v;
    }
    __syncthreads();

    float acc[8][4];
#pragma unroll
    for (int j = 0; j < 8; ++j)
#pragma unroll
        for (int k = 0; k < 4; ++k) acc[j][k] = 0.f;

    const float* W = Wb + (size_t)cls * (NHID * NPC);
    const int d0 = wave * 256;
#pragma unroll 4
    for (int dd = d0; dd < d0 + 256; ++dd) {
        float w[4];
        w[0] = W[dd * NPC + lane];
        w[1] = W[dd * NPC + lane + 64];
        w[2] = W[dd * NPC + lane + 128];
        w[3] = (lane + 192 < NPC) ? W[dd * NPC + lane + 192] : 0.f;  // lane < 33
        float4 a = *(const float4*)&smem[dd * 12 + 0];
        float4 b = *(const float4*)&smem[dd * 12 + 4];
        float xi[8] = {a.x, a.y, a.z, a.w, b.x, b.y, b.z, b.w};
#pragma unroll
        for (int j = 0; j < 8; ++j)
#pragma unroll
            for (int k = 0; k < 4; ++k) acc[j][k] += xi[j] * w[k];
    }
    __syncthreads();

    float* red = smem; // red[w][j][232]
#pragma unroll
    for (int j = 0; j < 8; ++j)
#pragma unroll
        for (int k = 0; k < 4; ++k) {
            int c = lane + 64 * k;
            if (c < NPC) red[(wave * 8 + j) * 232 + c] = acc[j][k];
        }
    __syncthreads();

    for (int jj = 0; jj < 2; ++jj) {
        const int j = wave * 2 + jj;
        if (j >= nt) continue;          // wave-uniform (nt uniform per block)
        const int s = order[s0 + j];
        float v[4];
#pragma unroll
        for (int k = 0; k < 4; ++k) {
            int c = lane + 64 * k;
            v[k] = (c < NPC)
                     ? (red[(0 * 8 + j) * 232 + c] + red[(1 * 8 + j) * 232 + c] +
                        red[(2 * 8 + j) * 232 + c] + red[(3 * 8 + j) * 232 + c] +
                        bb[cls * NPC + c])
                     : -INFINITY;
        }
        float m = fmaxf(fmaxf(v[0], v[1]), fmaxf(v[2], v[3]));
        for (int o = 32; o > 0; o >>= 1) m = fmaxf(m, __shfl_xor(m, o));
        float e = expf(v[0] - m) + expf(v[1] - m) + expf(v[2] - m) + expf(v[3] - m);
        for (int o = 32; o > 0; o >>= 1) e += __shfl_xor(e, o);
        const int pb = labels[s] % NPC;
        if (lane == (pb & 63))
            out[s] = ptop[s] * (expf(v[pb >> 6] - m) / e);
    }
}

// ---------------------------------------------------------------------------
extern "C" void kernel_launch(void* const* d_in, const int* in_sizes, int n_in,
                              void* d_out, int out_size, void* d_ws, size_t ws_size,
                              hipStream_t stream)
{
    const float* X      = (const float*)d_in[0];
    const int*   labels = (const int*)  d_in[1];
    const float* Wt     = (const float*)d_in[2];
    const float* bt     = (const float*)d_in[3];
    const float* Wb     = (const float*)d_in[4];
    const float* bb     = (const float*)d_in[5];
    float* out = (float*)d_out;
    int*   ws  = (int*)d_ws;
    float* ptop = (float*)((char*)d_ws + WS_PTOP_OFS);

    hipLaunchKernelGGL(k0_group, dim3(1), dim3(256), 0, stream, labels, ws);
    hipLaunchKernelGGL(k1_top, dim3(BATCH / 8), dim3(256), 0, stream,
                       X, labels, Wt, bt, ptop);
    hipLaunchKernelGGL(k2_bottom, dim3(MAX_ITEMS), dim3(256), 0, stream,
                       X, labels, Wb, bb, ws, ptop, out);
}

// Round 2
// 330.410 us; speedup vs baseline: 1.0978x; 1.0978x over previous
//
#include <hip/hip_runtime.h>
#include <math.h>

#define NTOK 50257
#define NHID 1024
#define NPC  225
#define NCLS 224
#define BATCH 1024

// ws layout (bytes):
//   0     : int   nitems
//   64    : int   order[1024]      (sample ids sorted by class)
//   8192  : int4  items[384]       (cls, s0, nt, 0)
//   16384 : float p_top[1024]
#define WS_ORDER_OFS 16      // in ints
#define WS_ITEMS_OFS 8192    // in bytes
#define WS_PTOP_OFS  16384   // in bytes
#define MAX_ITEMS    352

// ---------------------------------------------------------------------------
// K0: group samples by class, build work items (<=8 samples each)
// ---------------------------------------------------------------------------
__global__ __launch_bounds__(256) void k0_group(const int* __restrict__ labels,
                                                int* __restrict__ ws)
{
    __shared__ int cnt[256];
    __shared__ int scan[256];
    __shared__ int iscan[256];
    __shared__ int cur[256];
    const int tid = threadIdx.x;

    cnt[tid] = 0;
    __syncthreads();
    for (int i = tid; i < BATCH; i += 256)
        atomicAdd(&cnt[labels[i] / NPC], 1);
    __syncthreads();

    const int myc = (tid < NCLS) ? cnt[tid] : 0;
    const int myi = (myc + 7) >> 3;   // items for this class
    scan[tid]  = myc;
    iscan[tid] = myi;
    __syncthreads();
    // Hillis-Steele inclusive scans
    for (int off = 1; off < 256; off <<= 1) {
        int a = (tid >= off) ? scan[tid - off]  : 0;
        int b = (tid >= off) ? iscan[tid - off] : 0;
        __syncthreads();
        scan[tid]  += a;
        iscan[tid] += b;
        __syncthreads();
    }
    const int sbase = scan[tid]  - myc;   // exclusive prefix
    const int ibase = iscan[tid] - myi;
    if (tid == 255) ws[0] = iscan[255];
    cur[tid] = sbase;

    int4* items = (int4*)((char*)ws + WS_ITEMS_OFS);
    if (tid < NCLS) {
        for (int t = 0; t < myi; ++t)
            items[ibase + t] = make_int4(tid, sbase + 8 * t, min(8, myc - 8 * t), 0);
    }
    __syncthreads();

    int* order = ws + WS_ORDER_OFS;
    for (int i = tid; i < BATCH; i += 256) {
        int c = labels[i] / NPC;
        int p = atomicAdd(&cur[c], 1);
        order[p] = i;
    }
}

// ---------------------------------------------------------------------------
// Shared 8-sample block body: 512 threads = 8 waves, wave w covers d-rows
// [128w, 128w+128). Register prefetch of next weight row; two-stage LDS
// reduction; per-wave softmax (wave w handles sample w).
// smem: staging in_t[1024][12] (12288 f) reused as red[4][8][232] (7424 f).
// ---------------------------------------------------------------------------
template <int LD, int COLS>
__device__ __forceinline__ void block_matvec8_softmax(
    float* __restrict__ sm,            // 12288 floats
    const float* __restrict__ W,       // [1024][LD]
    const float* __restrict__ bias,    // [COLS]
    int wave, int lane,
    int nt,                            // active samples (<=8)
    const int* __restrict__ s_ids,     // sample ids per slot j (global)
    const int* __restrict__ labels,
    bool bottom,                       // false: top (write ptop), true: bottom
    const float* __restrict__ ptop,
    float* __restrict__ outp)          // ptop (top) or out (bottom)
{
    float acc[8][4];
#pragma unroll
    for (int j = 0; j < 8; ++j)
#pragma unroll
        for (int k = 0; k < 4; ++k) acc[j][k] = 0.f;

    const int c0 = lane, c1 = lane + 64, c2 = lane + 128, c3 = lane + 192;
    const bool m3 = (c3 < COLS);
    const int d0 = wave * 128;
    const float* Wr = W + (size_t)d0 * LD;

    float w0 = Wr[c0], w1 = Wr[c1], w2 = Wr[c2], w3 = m3 ? Wr[c3] : 0.f;
#pragma unroll 4
    for (int dd = 0; dd < 128; ++dd) {
        const float cw0 = w0, cw1 = w1, cw2 = w2, cw3 = w3;
        // prefetch next row (clamped so last iter re-reads row 127, no OOB)
        const float* nr = Wr + (size_t)min(dd + 1, 127) * LD;
        w0 = nr[c0]; w1 = nr[c1]; w2 = nr[c2]; w3 = m3 ? nr[c3] : 0.f;
        const float4 a = *(const float4*)&sm[(d0 + dd) * 12 + 0];
        const float4 b = *(const float4*)&sm[(d0 + dd) * 12 + 4];
        const float xi[8] = {a.x, a.y, a.z, a.w, b.x, b.y, b.z, b.w};
#pragma unroll
        for (int j = 0; j < 8; ++j) {
            acc[j][0] = fmaf(xi[j], cw0, acc[j][0]);
            acc[j][1] = fmaf(xi[j], cw1, acc[j][1]);
            acc[j][2] = fmaf(xi[j], cw2, acc[j][2]);
            acc[j][3] = fmaf(xi[j], cw3, acc[j][3]);
        }
    }
    __syncthreads();   // all waves done reading staging

    float* red = sm;   // red[w][j][232], w in 0..3
    if (wave >= 4) {
#pragma unroll
        for (int j = 0; j < 8; ++j)
#pragma unroll
            for (int k = 0; k < 4; ++k) {
                int c = lane + 64 * k;
                if (c < COLS) red[((wave - 4) * 8 + j) * 232 + c] = acc[j][k];
            }
    }
    __syncthreads();
    if (wave < 4) {
#pragma unroll
        for (int j = 0; j < 8; ++j)
#pragma unroll
            for (int k = 0; k < 4; ++k) {
                int c = lane + 64 * k;
                if (c < COLS)
                    red[(wave * 8 + j) * 232 + c] += acc[j][k];
            }
    }
    __syncthreads();

    // softmax: wave w handles sample slot j = w
    const int j = wave;
    if (j < nt) {
        const int s = s_ids[j];
        float v[4];
#pragma unroll
        for (int k = 0; k < 4; ++k) {
            int c = lane + 64 * k;
            v[k] = (c < COLS)
                     ? (red[(0 * 8 + j) * 232 + c] + red[(1 * 8 + j) * 232 + c] +
                        red[(2 * 8 + j) * 232 + c] + red[(3 * 8 + j) * 232 + c] +
                        bias[c])
                     : -INFINITY;
        }
        float m = fmaxf(fmaxf(v[0], v[1]), fmaxf(v[2], v[3]));
        for (int o = 32; o > 0; o >>= 1) m = fmaxf(m, __shfl_xor(m, o));
        float e = expf(v[0] - m) + expf(v[1] - m) + expf(v[2] - m) + expf(v[3] - m);
        for (int o = 32; o > 0; o >>= 1) e += __shfl_xor(e, o);
        const int lab = labels[s];
        const int tgt = bottom ? (lab % NPC) : (lab / NPC);
        if (lane == (tgt & 63)) {
            float p = expf(v[tgt >> 6] - m) / e;
            outp[s] = bottom ? (ptop[s] * p) : p;
        }
    }
}

// ---------------------------------------------------------------------------
// K1: top logits + softmax -> p_top[s].  8 samples/block, 512 threads.
// ---------------------------------------------------------------------------
__global__ __launch_bounds__(512) void k1_top(const float* __restrict__ X,
                                              const int* __restrict__ labels,
                                              const float* __restrict__ Wt,
                                              const float* __restrict__ bt,
                                              float* __restrict__ ptop)
{
    __shared__ __align__(16) float smem[12288];
    const int tid  = threadIdx.x;
    const int wave = tid >> 6;
    const int lane = tid & 63;
    const int sbase = blockIdx.x * 8;

    // stage 8 rows transposed: smem[dd*12 + j] = X[sbase+j][dd]
    for (int idx = tid; idx < 2048; idx += 512) {
        const int j  = idx >> 8;           // 0..7
        const int d4 = idx & 255;          // float4 index in row
        const float4 v = ((const float4*)&X[(size_t)(sbase + j) * NHID])[d4];
        smem[(4 * d4 + 0) * 12 + j] = v.x;
        smem[(4 * d4 + 1) * 12 + j] = v.y;
        smem[(4 * d4 + 2) * 12 + j] = v.z;
        smem[(4 * d4 + 3) * 12 + j] = v.w;
    }
    __syncthreads();

    int s_ids[8];
#pragma unroll
    for (int j = 0; j < 8; ++j) s_ids[j] = sbase + j;

    block_matvec8_softmax<NCLS, NCLS>(smem, Wt, bt, wave, lane, 8, s_ids,
                                      labels, false, nullptr, ptop);
}

// ---------------------------------------------------------------------------
// K2: bottom logits per class-item + softmax + final multiply -> out[s]
// ---------------------------------------------------------------------------
__global__ __launch_bounds__(512) void k2_bottom(const float* __restrict__ X,
                                                 const int* __restrict__ labels,
                                                 const float* __restrict__ Wb,
                                                 const float* __restrict__ bb,
                                                 const int* __restrict__ ws,
                                                 const float* __restrict__ ptop,
                                                 float* __restrict__ out)
{
    __shared__ __align__(16) float smem[12288];
    const int nitems = ws[0];
    if ((int)blockIdx.x >= nitems) return;
    const int4 item = ((const int4*)((const char*)ws + WS_ITEMS_OFS))[blockIdx.x];
    const int cls = item.x, s0 = item.y, nt = item.z;
    const int* order = ws + WS_ORDER_OFS;

    const int tid  = threadIdx.x;
    const int wave = tid >> 6;
    const int lane = tid & 63;

    int s_ids[8];
#pragma unroll
    for (int j = 0; j < 8; ++j) s_ids[j] = (j < nt) ? order[s0 + j] : 0;

    // stage up to 8 gathered rows (zero-pad unused slots)
    for (int idx = tid; idx < 2048; idx += 512) {
        const int j  = idx >> 8;
        const int d4 = idx & 255;
        float4 v = make_float4(0.f, 0.f, 0.f, 0.f);
        if (j < nt) v = ((const float4*)&X[(size_t)s_ids[j] * NHID])[d4];
        smem[(4 * d4 + 0) * 12 + j] = v.x;
        smem[(4 * d4 + 1) * 12 + j] = v.y;
        smem[(4 * d4 + 2) * 12 + j] = v.z;
        smem[(4 * d4 + 3) * 12 + j] = v.w;
    }
    __syncthreads();

    const float* W = Wb + (size_t)cls * (NHID * NPC);
    block_matvec8_softmax<NPC, NPC>(smem, W, bb + cls * NPC, wave, lane, nt,
                                    s_ids, labels, true, ptop, out);
}

// ---------------------------------------------------------------------------
extern "C" void kernel_launch(void* const* d_in, const int* in_sizes, int n_in,
                              void* d_out, int out_size, void* d_ws, size_t ws_size,
                              hipStream_t stream)
{
    const float* X      = (const float*)d_in[0];
    const int*   labels = (const int*)  d_in[1];
    const float* Wt     = (const float*)d_in[2];
    const float* bt     = (const float*)d_in[3];
    const float* Wb     = (const float*)d_in[4];
    const float* bb     = (const float*)d_in[5];
    float* out = (float*)d_out;
    int*   ws  = (int*)d_ws;
    float* ptop = (float*)((char*)d_ws + WS_PTOP_OFS);

    hipLaunchKernelGGL(k0_group, dim3(1), dim3(256), 0, stream, labels, ws);
    hipLaunchKernelGGL(k1_top, dim3(BATCH / 8), dim3(512), 0, stream,
                       X, labels, Wt, bt, ptop);
    hipLaunchKernelGGL(k2_bottom, dim3(MAX_ITEMS), dim3(512), 0, stream,
                       X, labels, Wb, bb, ws, ptop, out);
}

// Round 3
// 309.445 us; speedup vs baseline: 1.1722x; 1.0678x over previous
//
#include <hip/hip_runtime.h>
#include <math.h>

#define NTOK 50257
#define NHID 1024
#define NPC  225
#define NCLS 224
#define BATCH 1024

// ws layout (bytes):
//   0     : int   nitems
//   64    : int   order[1024]      (sample ids sorted by class)
//   8192  : int4  items[384]       (cls, s0, nt, 0)
//   16384 : float p_top[1024]
#define WS_ORDER_OFS 16      // in ints
#define WS_ITEMS_OFS 8192    // in bytes
#define WS_PTOP_OFS  16384   // in bytes
#define MAX_ITEMS    352

// ---------------------------------------------------------------------------
// Grouping (runs as block BATCH/8 of k1): histogram by class, scans, scatter.
// ---------------------------------------------------------------------------
__device__ __forceinline__ void group_samples(const int* __restrict__ labels,
                                              int* __restrict__ ws, int tid)
{
    __shared__ int cnt[256];
    __shared__ int scan[256];
    __shared__ int iscan[256];
    __shared__ int cur[256];

    if (tid < 256) cnt[tid] = 0;
    __syncthreads();
    for (int i = tid; i < BATCH; i += 512)
        atomicAdd(&cnt[labels[i] / NPC], 1);
    __syncthreads();

    int myc = 0, myi = 0;
    if (tid < 256) {
        myc = (tid < NCLS) ? cnt[tid] : 0;
        myi = (myc + 7) >> 3;
        scan[tid]  = myc;
        iscan[tid] = myi;
    }
    __syncthreads();
    for (int off = 1; off < 256; off <<= 1) {
        int a = 0, b = 0;
        if (tid < 256 && tid >= off) { a = scan[tid - off]; b = iscan[tid - off]; }
        __syncthreads();
        if (tid < 256) { scan[tid] += a; iscan[tid] += b; }
        __syncthreads();
    }
    if (tid < 256) {
        const int sbase = scan[tid]  - myc;
        const int ibase = iscan[tid] - myi;
        if (tid == 255) ws[0] = iscan[255];
        cur[tid] = sbase;
        int4* items = (int4*)((char*)ws + WS_ITEMS_OFS);
        if (tid < NCLS)
            for (int t = 0; t < myi; ++t)
                items[ibase + t] = make_int4(tid, sbase + 8 * t, min(8, myc - 8 * t), 0);
    }
    __syncthreads();
    int* order = ws + WS_ORDER_OFS;
    for (int i = tid; i < BATCH; i += 512) {
        int c = labels[i] / NPC;
        int p = atomicAdd(&cur[c], 1);
        order[p] = i;
    }
}

// ---------------------------------------------------------------------------
// Shared 8-sample matvec+softmax body. 512 threads = 8 waves; wave w covers
// d-rows [128w, 128w+128). 4-row-deep register prefetch pipeline (16 loads
// in flight per wave = 4 KB; 32 KB/CU >> 9 KB BW*latency product).
// smem: staging in_t[1024][12] (12288 f) reused as red[4][8][232].
// ---------------------------------------------------------------------------
template <int LD, int COLS, bool NT>
__device__ __forceinline__ void block_matvec8_softmax(
    float* __restrict__ sm,
    const float* __restrict__ W,       // [1024][LD]
    const float* __restrict__ bias,    // [COLS]
    int wave, int lane, int nt,
    const int* __restrict__ s_ids,
    const int* __restrict__ labels,
    bool bottom,
    const float* __restrict__ ptop,
    float* __restrict__ outp)
{
    float acc[8][4];
#pragma unroll
    for (int j = 0; j < 8; ++j)
#pragma unroll
        for (int k = 0; k < 4; ++k) acc[j][k] = 0.f;

    const int c0 = lane, c1 = lane + 64, c2 = lane + 128, c3 = lane + 192;
    const bool m3 = (c3 < COLS);
    const int d0 = wave * 128;
    const float* Wr = W + (size_t)d0 * LD;

    auto ldrow = [&](int r, float* o) {
        const float* p = Wr + (size_t)r * LD;
        if (NT) {
            o[0] = __builtin_nontemporal_load(p + c0);
            o[1] = __builtin_nontemporal_load(p + c1);
            o[2] = __builtin_nontemporal_load(p + c2);
            o[3] = m3 ? __builtin_nontemporal_load(p + c3) : 0.f;
        } else {
            o[0] = p[c0]; o[1] = p[c1]; o[2] = p[c2];
            o[3] = m3 ? p[c3] : 0.f;
        }
    };

    float wbuf[4][4];
    ldrow(0, wbuf[0]); ldrow(1, wbuf[1]); ldrow(2, wbuf[2]); ldrow(3, wbuf[3]);

#pragma unroll 4
    for (int dd = 0; dd < 128; ++dd) {
        const int slot = dd & 3;
        const float cw0 = wbuf[slot][0], cw1 = wbuf[slot][1],
                    cw2 = wbuf[slot][2], cw3 = wbuf[slot][3];
        ldrow(min(dd + 4, 127), wbuf[slot]);   // clamped: tail re-reads row 127 (L1 hit)
        const float4 a = *(const float4*)&sm[(d0 + dd) * 12 + 0];
        const float4 b = *(const float4*)&sm[(d0 + dd) * 12 + 4];
        const float xi[8] = {a.x, a.y, a.z, a.w, b.x, b.y, b.z, b.w};
#pragma unroll
        for (int j = 0; j < 8; ++j) {
            acc[j][0] = fmaf(xi[j], cw0, acc[j][0]);
            acc[j][1] = fmaf(xi[j], cw1, acc[j][1]);
            acc[j][2] = fmaf(xi[j], cw2, acc[j][2]);
            acc[j][3] = fmaf(xi[j], cw3, acc[j][3]);
        }
    }
    __syncthreads();   // all waves done reading staging

    float* red = sm;   // red[w][j][232], w in 0..3
    if (wave >= 4) {
#pragma unroll
        for (int j = 0; j < 8; ++j)
#pragma unroll
            for (int k = 0; k < 4; ++k) {
                int c = lane + 64 * k;
                if (c < COLS) red[((wave - 4) * 8 + j) * 232 + c] = acc[j][k];
            }
    }
    __syncthreads();
    if (wave < 4) {
#pragma unroll
        for (int j = 0; j < 8; ++j)
#pragma unroll
            for (int k = 0; k < 4; ++k) {
                int c = lane + 64 * k;
                if (c < COLS) red[(wave * 8 + j) * 232 + c] += acc[j][k];
            }
    }
    __syncthreads();

    const int j = wave;   // wave w finalizes sample slot w
    if (j < nt) {
        const int s = s_ids[j];
        float v[4];
#pragma unroll
        for (int k = 0; k < 4; ++k) {
            int c = lane + 64 * k;
            v[k] = (c < COLS)
                     ? (red[(0 * 8 + j) * 232 + c] + red[(1 * 8 + j) * 232 + c] +
                        red[(2 * 8 + j) * 232 + c] + red[(3 * 8 + j) * 232 + c] +
                        bias[c])
                     : -INFINITY;
        }
        float m = fmaxf(fmaxf(v[0], v[1]), fmaxf(v[2], v[3]));
        for (int o = 32; o > 0; o >>= 1) m = fmaxf(m, __shfl_xor(m, o));
        float e = expf(v[0] - m) + expf(v[1] - m) + expf(v[2] - m) + expf(v[3] - m);
        for (int o = 32; o > 0; o >>= 1) e += __shfl_xor(e, o);
        const int lab = labels[s];
        const int tgt = bottom ? (lab % NPC) : (lab / NPC);
        if (lane == (tgt & 63)) {
            float p = expf(v[tgt >> 6] - m) / e;
            outp[s] = bottom ? (ptop[s] * p) : p;
        }
    }
}

// ---------------------------------------------------------------------------
// K1: blocks 0..127 -> top softmax (8 samples each); block 128 -> grouping.
// ---------------------------------------------------------------------------
__global__ __launch_bounds__(512) void k1_top(const float* __restrict__ X,
                                              const int* __restrict__ labels,
                                              const float* __restrict__ Wt,
                                              const float* __restrict__ bt,
                                              float* __restrict__ ptop,
                                              int* __restrict__ ws)
{
    __shared__ __align__(16) float smem[12288];
    const int tid = threadIdx.x;

    if (blockIdx.x == BATCH / 8) {     // grouping block
        group_samples(labels, ws, tid);
        return;
    }

    const int wave = tid >> 6;
    const int lane = tid & 63;
    const int sbase = blockIdx.x * 8;

    for (int idx = tid; idx < 2048; idx += 512) {
        const int j  = idx >> 8;
        const int d4 = idx & 255;
        const float4 v = ((const float4*)&X[(size_t)(sbase + j) * NHID])[d4];
        smem[(4 * d4 + 0) * 12 + j] = v.x;
        smem[(4 * d4 + 1) * 12 + j] = v.y;
        smem[(4 * d4 + 2) * 12 + j] = v.z;
        smem[(4 * d4 + 3) * 12 + j] = v.w;
    }
    __syncthreads();

    int s_ids[8];
#pragma unroll
    for (int j = 0; j < 8; ++j) s_ids[j] = sbase + j;

    block_matvec8_softmax<NCLS, NCLS, false>(smem, Wt, bt, wave, lane, 8, s_ids,
                                             labels, false, nullptr, ptop);
}

// ---------------------------------------------------------------------------
// K2: bottom logits per class-item + softmax + final multiply -> out[s]
// ---------------------------------------------------------------------------
__global__ __launch_bounds__(512) void k2_bottom(const float* __restrict__ X,
                                                 const int* __restrict__ labels,
                                                 const float* __restrict__ Wb,
                                                 const float* __restrict__ bb,
                                                 const int* __restrict__ ws,
                                                 const float* __restrict__ ptop,
                                                 float* __restrict__ out)
{
    __shared__ __align__(16) float smem[12288];
    const int nitems = ws[0];
    if ((int)blockIdx.x >= nitems) return;
    const int4 item = ((const int4*)((const char*)ws + WS_ITEMS_OFS))[blockIdx.x];
    const int cls = item.x, s0 = item.y, nt = item.z;
    const int* order = ws + WS_ORDER_OFS;

    const int tid  = threadIdx.x;
    const int wave = tid >> 6;
    const int lane = tid & 63;

    int s_ids[8];
#pragma unroll
    for (int j = 0; j < 8; ++j) s_ids[j] = (j < nt) ? order[s0 + j] : 0;

    for (int idx = tid; idx < 2048; idx += 512) {
        const int j  = idx >> 8;
        const int d4 = idx & 255;
        float4 v = make_float4(0.f, 0.f, 0.f, 0.f);
        if (j < nt) v = ((const float4*)&X[(size_t)s_ids[j] * NHID])[d4];
        smem[(4 * d4 + 0) * 12 + j] = v.x;
        smem[(4 * d4 + 1) * 12 + j] = v.y;
        smem[(4 * d4 + 2) * 12 + j] = v.z;
        smem[(4 * d4 + 3) * 12 + j] = v.w;
    }
    __syncthreads();

    const float* W = Wb + (size_t)cls * (NHID * NPC);
    block_matvec8_softmax<NPC, NPC, true>(smem, W, bb + cls * NPC, wave, lane,
                                          nt, s_ids, labels, true, ptop, out);
}

// ---------------------------------------------------------------------------
extern "C" void kernel_launch(void* const* d_in, const int* in_sizes, int n_in,
                              void* d_out, int out_size, void* d_ws, size_t ws_size,
                              hipStream_t stream)
{
    const float* X      = (const float*)d_in[0];
    const int*   labels = (const int*)  d_in[1];
    const float* Wt     = (const float*)d_in[2];
    const float* bt     = (const float*)d_in[3];
    const float* Wb     = (const float*)d_in[4];
    const float* bb     = (const float*)d_in[5];
    float* out = (float*)d_out;
    int*   ws  = (int*)d_ws;
    float* ptop = (float*)((char*)d_ws + WS_PTOP_OFS);

    // k1: 128 matvec blocks + 1 grouping block (independent work, one launch)
    hipLaunchKernelGGL(k1_top, dim3(BATCH / 8 + 1), dim3(512), 0, stream,
                       X, labels, Wt, bt, ptop, ws);
    hipLaunchKernelGGL(k2_bottom, dim3(MAX_ITEMS), dim3(512), 0, stream,
                       X, labels, Wb, bb, ws, ptop, out);
}